// Round 1
// 169.557 us; speedup vs baseline: 1.1715x; 1.1715x over previous
//
#include <hip/hip_runtime.h>
#include <stdint.h>

// ---------------------------------------------------------------------------
// 2D DCT-II (unnormalized, 4096x4096 fp32), FFT path, v5:
//   Row pass unchanged (pair-packed 4096-pt FFT in LDS + Hermitian/expk
//   epilogue), but the column pass is now a FOUR-STEP FFT:
//     FFT_4096(col) = FFT_64 (over n2, stride-64 rows)  -> twiddle W4096^{n1 k2}
//                   -> FFT_64 (over n1, contiguous rows)
//   which removes BOTH transpose kernels (4 global sweeps -> 3).
// Data flow (d_out used as scratch, same ws budget as v4):
//   1. dct_rows   : x  -> out  (V = row-DCT result, with the NEXT pass's
//                   Makhoul row-permute folded into the output row index:
//                   row 2b -> b, row 2b+1 -> 4095-b)
//   2. col_fft1   : out -> B1  (per n1: 64-pt FFT over n2 + 4-step twiddle;
//                   H[n1][k2] stored at row 64*k2+n1 so pass 3 reads are
//                   contiguous)
//   3. col_fft2   : B1 -> out  (per k2-pair {k2,64-k2}: 64-pt FFT over n1,
//                   Hermitian pairs are block-local, expk epilogue, real out)
// Columns are pair-packed (2c,2c+1) as re/im; all global segments are 256 B;
// LDS mapped cp-fast => conflict-free without swizzle.
// ---------------------------------------------------------------------------

#define NF 4096

__device__ __forceinline__ int physi(int e) { return e ^ ((e >> 4) & 15); }

__device__ __forceinline__ float2 cadd(float2 a, float2 b) {
    float2 r; r.x = a.x + b.x; r.y = a.y + b.y; return r;
}
__device__ __forceinline__ float2 csub(float2 a, float2 b) {
    float2 r; r.x = a.x - b.x; r.y = a.y - b.y; return r;
}
__device__ __forceinline__ float2 cmulc(float2 a, float2 b) {
    float2 r; r.x = a.x * b.x - a.y * b.y; r.y = a.x * b.y + a.y * b.x; return r;
}
__device__ __forceinline__ float2 rotm(float2 a) {  // -i * a
    float2 r; r.x = a.y; r.y = -a.x; return r;
}

// tw: stages t=1..3, w[p][u] = exp(-2*pi*i*p*u/(8*Ls)), Ls=8,64,512.
//     (first 64 entries, Ls=8, double as the 64-pt FFT stage-1 twiddles)
// ek: expk[k] = (cos(pi*k/8192), sin(pi*k/8192)), 4096 entries.
__global__ __launch_bounds__(256) void setup_tables(float* __restrict__ tw,
                                                    float* __restrict__ ek) {
    int idx = blockIdx.x * 256 + threadIdx.x;
    if (idx < 4672) {
        int Ls, rel;
        if (idx < 64)       { Ls = 8;   rel = idx; }
        else if (idx < 576) { Ls = 64;  rel = idx - 64; }
        else                { Ls = 512; rel = idx - 576; }
        int p = rel >> 3, u = rel & 7;
        float phi = (float)(p * u) * (6.283185307179586f / (8.0f * (float)Ls));
        float s, c; __sincosf(phi, &s, &c);
        tw[2 * idx]     = c;
        tw[2 * idx + 1] = -s;
    } else if (idx < 8768) {
        int k = idx - 4672;
        float th = (float)k * (3.141592653589793f / 8192.0f);
        float s, c; __sincosf(th, &s, &c);
        ek[2 * k]     = c;
        ek[2 * k + 1] = s;
    }
}

#define RADIX8(x, E0, E1, E2, E3, O0, g1, g2, g3)                              \
    float2 t0 = cadd(x[0], x[4]), t1 = csub(x[0], x[4]);                       \
    float2 t2 = cadd(x[2], x[6]), t3 = csub(x[2], x[6]);                       \
    float2 E0 = cadd(t0, t2), E2 = csub(t0, t2);                               \
    float2 r3 = rotm(t3);                                                      \
    float2 E1 = cadd(t1, r3), E3 = csub(t1, r3);                               \
    float2 s0 = cadd(x[1], x[5]), s1 = csub(x[1], x[5]);                       \
    float2 s2 = cadd(x[3], x[7]), s3 = csub(x[3], x[7]);                       \
    float2 O0 = cadd(s0, s2), O2 = csub(s0, s2);                               \
    float2 r7 = rotm(s3);                                                      \
    float2 O1 = cadd(s1, r7), O3 = csub(s1, r7);                               \
    const float SQ = 0.7071067811865476f;                                      \
    float2 g1; g1.x = SQ * (O1.x + O1.y); g1.y = SQ * (O1.y - O1.x);           \
    float2 g2 = rotm(O2);                                                      \
    float2 g3; g3.x = SQ * (O3.y - O3.x); g3.y = -SQ * (O3.x + O3.y);

// One workgroup (512 thr) = TWO input rows (2b, 2b+1), pair-packed.
// Stage 0 applies the row-direction Makhoul gather; output rows are written
// PERMUTED for the next pass's column-Makhoul: row 2b -> b, row 2b+1 -> 4095-b.
__global__ __launch_bounds__(512) void dct_rows(const float* __restrict__ In,
                                                float* __restrict__ Out,
                                                const float* __restrict__ tw,
                                                const float* __restrict__ ek) {
    __shared__ float2 buf[NF];   // 32 KB
    const int j = threadIdx.x;   // butterfly job 0..511
    const int b = blockIdx.x;
    const float* in0 = In + (size_t)(2 * b) * NF;
    const float* in1 = in0 + NF;
    float* out0 = Out + (size_t)b * NF;            // sigma^-1(2b)   = b
    float* out1 = Out + (size_t)(4095 - b) * NF;   // sigma^-1(2b+1) = 4095-b

    float2 x[8];

    // ---- stage 0 (Ls=1): read pair z = v0 + i*v1 from global (Makhoul gather)
    #pragma unroll
    for (int k = 0; k < 8; ++k) {
        int n = j + 512 * k;
        int idx = (n < 2048) ? (2 * n) : (8191 - 2 * n);
        x[k].x = in0[idx];
        x[k].y = in1[idx];
    }
    {
        RADIX8(x, E0, E1, E2, E3, O0, g1, g2, g3)
        int wb = 8 * j;
        buf[physi(wb)]     = cadd(E0, O0);
        buf[physi(wb + 1)] = cadd(E1, g1);
        buf[physi(wb + 2)] = cadd(E2, g2);
        buf[physi(wb + 3)] = cadd(E3, g3);
        buf[physi(wb + 4)] = csub(E0, O0);
        buf[physi(wb + 5)] = csub(E1, g1);
        buf[physi(wb + 6)] = csub(E2, g2);
        buf[physi(wb + 7)] = csub(E3, g3);
    }
    __syncthreads();

    // ---- stages 1..2: read->barrier->write->barrier
    #pragma unroll
    for (int t = 1; t < 3; ++t) {
        const int Ls = 1 << (3 * t);
        const int twoff = (t == 1) ? 0 : 64;
        const int p = j & (Ls - 1);
        const int q = j >> (3 * t);
        #pragma unroll
        for (int k = 0; k < 8; ++k)
            x[k] = buf[physi(j + 512 * k)];
        const float2* twp = (const float2*)tw + twoff + p * 8;
        #pragma unroll
        for (int k = 1; k < 8; ++k)
            x[k] = cmulc(x[k], twp[k]);
        RADIX8(x, E0, E1, E2, E3, O0, g1, g2, g3)
        __syncthreads();
        int wb = p + 8 * Ls * q;
        buf[physi(wb)]          = cadd(E0, O0);
        buf[physi(wb + Ls)]     = cadd(E1, g1);
        buf[physi(wb + 2 * Ls)] = cadd(E2, g2);
        buf[physi(wb + 3 * Ls)] = cadd(E3, g3);
        buf[physi(wb + 4 * Ls)] = csub(E0, O0);
        buf[physi(wb + 5 * Ls)] = csub(E1, g1);
        buf[physi(wb + 6 * Ls)] = csub(E2, g2);
        buf[physi(wb + 7 * Ls)] = csub(E3, g3);
        __syncthreads();
    }

    // ---- stage 3 (Ls=512): read-set == write-set per thread, no mid barrier
    float2 o[8];
    {
        #pragma unroll
        for (int k = 0; k < 8; ++k)
            x[k] = buf[physi(j + 512 * k)];
        const float2* twp = (const float2*)tw + 576 + j * 8;
        #pragma unroll
        for (int k = 1; k < 8; ++k)
            x[k] = cmulc(x[k], twp[k]);
        RADIX8(x, E0, E1, E2, E3, O0, g1, g2, g3)
        o[0] = cadd(E0, O0); o[1] = cadd(E1, g1);
        o[2] = cadd(E2, g2); o[3] = cadd(E3, g3);
        o[4] = csub(E0, O0); o[5] = csub(E1, g1);
        o[6] = csub(E2, g2); o[7] = csub(E3, g3);
        #pragma unroll
        for (int r = 0; r < 8; ++r)
            buf[physi(j + 512 * r)] = o[r];   // own slots only
    }
    __syncthreads();

    // ---- epilogue: Zk = o[i] (regs); Zm from partner via LDS
    #pragma unroll
    for (int i = 0; i < 8; ++i) {
        int k = j + 512 * i;
        int m = (NF - k) & (NF - 1);
        float2 Zk = o[i];
        float2 Zm = buf[physi(m)];
        float2 E = ((const float2*)ek)[k];
        out0[k] = 0.5f * ((Zk.x + Zm.x) * E.x + (Zk.y - Zm.y) * E.y);
        out1[k] = 0.5f * ((Zk.y + Zm.y) * E.x - (Zk.x - Zm.x) * E.y);
    }
}

// ---------------------------------------------------------------------------
// Column pass, four-step step 1. One block = one n1 residue (blockIdx.y) x
// one 64-column tile (blockIdx.x). 256 threads: cp = t&31 (column float2
// within tile, lane-fast => conflict-free LDS, 256 B global segments),
// j = t>>5 (radix-8 butterfly job of the 64-pt FFT).
// Reads V rows n1+64*n2 (n2 = j+8k), 64-pt FFT over n2 in regs with ONE LDS
// exchange, applies W4096^{n1*k2}, stores H to S row 64*k2+n1.
// ---------------------------------------------------------------------------
__global__ __launch_bounds__(256) void col_fft1(const float* __restrict__ V,
                                                float* __restrict__ S,
                                                const float* __restrict__ tw) {
    __shared__ float2 T[64][32];   // 16 KB
    const int ct = blockIdx.x, n1 = blockIdx.y;
    const int t = threadIdx.x;
    const int cp = t & 31, j = t >> 5;
    const float2* inb = (const float2*)V + (size_t)ct * 32 + cp;

    float2 x[8];
    #pragma unroll
    for (int k = 0; k < 8; ++k) {
        int row = n1 + 64 * (j + 8 * k);
        x[k] = inb[(size_t)row * 2048];
    }
    {   // stage A (Ls=1): outputs to LDS rows 8j+i
        RADIX8(x, E0, E1, E2, E3, O0, g1, g2, g3)
        T[8 * j + 0][cp] = cadd(E0, O0);
        T[8 * j + 1][cp] = cadd(E1, g1);
        T[8 * j + 2][cp] = cadd(E2, g2);
        T[8 * j + 3][cp] = cadd(E3, g3);
        T[8 * j + 4][cp] = csub(E0, O0);
        T[8 * j + 5][cp] = csub(E1, g1);
        T[8 * j + 6][cp] = csub(E2, g2);
        T[8 * j + 7][cp] = csub(E3, g3);
    }
    __syncthreads();

    float2 o[8];
    {   // stage B (Ls=8): p=j, natural-order outputs k2 = j+8i
        #pragma unroll
        for (int k = 0; k < 8; ++k)
            x[k] = T[j + 8 * k][cp];
        const float2* twp = (const float2*)tw + j * 8;   // Ls=8 section
        #pragma unroll
        for (int k = 1; k < 8; ++k)
            x[k] = cmulc(x[k], twp[k]);
        RADIX8(x, E0, E1, E2, E3, O0, g1, g2, g3)
        o[0] = cadd(E0, O0); o[1] = cadd(E1, g1);
        o[2] = cadd(E2, g2); o[3] = cadd(E3, g3);
        o[4] = csub(E0, O0); o[5] = csub(E1, g1);
        o[6] = csub(E2, g2); o[7] = csub(E3, g3);
    }

    // four-step twiddle W4096^{n1*k2}, store to S row 64*k2+n1
    float2* outb = (float2*)S + (size_t)ct * 32 + cp;
    #pragma unroll
    for (int i = 0; i < 8; ++i) {
        int k2 = j + 8 * i;
        float phi = (float)(n1 * k2) * -1.5339807878856412e-3f;  // -2pi/4096
        float s, c; __sincosf(phi, &s, &c);
        float2 w; w.x = c; w.y = s;
        float2 h = cmulc(o[i], w);
        outb[(size_t)(64 * k2 + n1) * 2048] = h;
    }
}

// ---------------------------------------------------------------------------
// Column pass, four-step step 2 + Hermitian/expk epilogue. One block = the
// k2-pair {ga, gb} = {bp, 64-bp} (bp=0 -> {0,32}) x one 64-column tile.
// 512 threads: gi = t>>8 selects the group, j = (t>>5)&7, cp = t&31.
// Reads S rows 64*g+n1 (contiguous), 64-pt FFT over n1 -> Z[64*k1+g]; the
// Hermitian partner of k lives in the paired group => epilogue is block-local.
// ---------------------------------------------------------------------------
__global__ __launch_bounds__(512) void col_fft2(const float* __restrict__ S,
                                                float* __restrict__ Out,
                                                const float* __restrict__ tw,
                                                const float* __restrict__ ek) {
    __shared__ float2 T[2][64][32];   // 32 KB
    const int ct = blockIdx.x, bp = blockIdx.y;
    const int ga = bp, gb = (bp == 0) ? 32 : 64 - bp;
    const int t = threadIdx.x;
    const int cp = t & 31, j = (t >> 5) & 7, gi = t >> 8;
    const int g = gi ? gb : ga;
    const float2* inb = (const float2*)S + (size_t)ct * 32 + cp;

    float2 x[8];
    #pragma unroll
    for (int k = 0; k < 8; ++k)
        x[k] = inb[(size_t)(64 * g + j + 8 * k) * 2048];
    {   // stage A
        RADIX8(x, E0, E1, E2, E3, O0, g1, g2, g3)
        T[gi][8 * j + 0][cp] = cadd(E0, O0);
        T[gi][8 * j + 1][cp] = cadd(E1, g1);
        T[gi][8 * j + 2][cp] = cadd(E2, g2);
        T[gi][8 * j + 3][cp] = cadd(E3, g3);
        T[gi][8 * j + 4][cp] = csub(E0, O0);
        T[gi][8 * j + 5][cp] = csub(E1, g1);
        T[gi][8 * j + 6][cp] = csub(E2, g2);
        T[gi][8 * j + 7][cp] = csub(E3, g3);
    }
    __syncthreads();

    float2 o[8];
    {   // stage B: read rows j+8k, write rows j+8i (same per-thread set)
        #pragma unroll
        for (int k = 0; k < 8; ++k)
            x[k] = T[gi][j + 8 * k][cp];
        const float2* twp = (const float2*)tw + j * 8;
        #pragma unroll
        for (int k = 1; k < 8; ++k)
            x[k] = cmulc(x[k], twp[k]);
        RADIX8(x, E0, E1, E2, E3, O0, g1, g2, g3)
        o[0] = cadd(E0, O0); o[1] = cadd(E1, g1);
        o[2] = cadd(E2, g2); o[3] = cadd(E3, g3);
        o[4] = csub(E0, O0); o[5] = csub(E1, g1);
        o[6] = csub(E2, g2); o[7] = csub(E3, g3);
        #pragma unroll
        for (int i = 0; i < 8; ++i)
            T[gi][j + 8 * i][cp] = o[i];
    }
    __syncthreads();

    // epilogue: k = 64*(j+8i)+g; partner m = (4096-k)&4095 is in this block
    float2* outb = (float2*)Out + (size_t)ct * 32 + cp;
    #pragma unroll
    for (int i = 0; i < 8; ++i) {
        int k = 64 * (j + 8 * i) + g;
        int m = (NF - k) & (NF - 1);
        int gp = m & 63, k1p = m >> 6;
        float2 Zk = o[i];
        float2 Zm = T[(gp == ga) ? 0 : 1][k1p][cp];
        float2 E = ((const float2*)ek)[k];
        float2 r;
        r.x = 0.5f * ((Zk.x + Zm.x) * E.x + (Zk.y - Zm.y) * E.y);
        r.y = 0.5f * ((Zk.y + Zm.y) * E.x - (Zk.x - Zm.x) * E.y);
        outb[(size_t)k * 2048] = r;   // cols 2*(ct*32+cp), +1
    }
}

extern "C" void kernel_launch(void* const* d_in, const int* in_sizes, int n_in,
                              void* d_out, int out_size, void* d_ws, size_t ws_size,
                              hipStream_t stream) {
    const float* x = (const float*)d_in[0];
    float* out = (float*)d_out;

    float* tw = (float*)d_ws;           // 4672 float2 = 9344 floats
    float* ek = tw + 9344;              // 4096 float2 = 8192 floats
    float* B1 = ek + 8192;              // 4096*4096 floats (64 MB)
    if (ws_size < (size_t)70144 + (size_t)NF * NF * sizeof(float)) return;

    setup_tables<<<35, 256, 0, stream>>>(tw, ek);
    dct_rows<<<NF / 2, 512, 0, stream>>>(x, out, tw, ek);        // out = V
    col_fft1<<<dim3(64, 64), 256, 0, stream>>>(out, B1, tw);     // B1  = H
    col_fft2<<<dim3(64, 32), 512, 0, stream>>>(B1, out, tw, ek); // out = Z
}

// Round 4
// 169.008 us; speedup vs baseline: 1.1753x; 1.0032x over previous
//
#include <hip/hip_runtime.h>
#include <stdint.h>

// ---------------------------------------------------------------------------
// 2D DCT-II (unnormalized, 4096x4096 fp32), FFT path, v6c:
//   v6b + launch fix: dct_rows handles TWO rows per block (pair-packed), so
//   grid is NF/2 = 2048 (v6/v6b launched NF blocks -> OOB reads -> abort).
//   Row pass: RADIX-16 Stockham (16^3 = 4096): 3 stages, 2 LDS exchanges,
//   4 barriers. 256 threads per row-pair, 16 float2/thread.
//   Column pass: four-step FFT_64 x tw x FFT_64 (no transposes); col_fft1
//   twiddles from a 64-entry LDS table (64 sincos/block instead of 2048).
// Data flow (d_out used as scratch):
//   1. dct_rows   : x  -> out  (V = row-DCT, column-Makhoul folded into the
//                   output row index: row 2b -> b, row 2b+1 -> 4095-b)
//   2. col_fft1   : out -> B1  (per n1: 64-pt FFT over n2 + 4-step twiddle;
//                   H[n1][k2] at row 64*k2+n1 so pass 3 reads contiguous)
//   3. col_fft2   : B1 -> out  (per k2-pair {k2,64-k2}: 64-pt FFT over n1,
//                   Hermitian pairs block-local, expk epilogue, real out)
// ---------------------------------------------------------------------------

#define NF 4096

__device__ __forceinline__ int physi(int e) { return e ^ ((e >> 4) & 15); }

__device__ __forceinline__ float2 cadd(float2 a, float2 b) {
    float2 r; r.x = a.x + b.x; r.y = a.y + b.y; return r;
}
__device__ __forceinline__ float2 csub(float2 a, float2 b) {
    float2 r; r.x = a.x - b.x; r.y = a.y - b.y; return r;
}
__device__ __forceinline__ float2 cmulc(float2 a, float2 b) {
    float2 r; r.x = a.x * b.x - a.y * b.y; r.y = a.x * b.y + a.y * b.x; return r;
}
__device__ __forceinline__ float2 rotm(float2 a) {  // -i * a
    float2 r; r.x = a.y; r.y = -a.x; return r;
}

// tw layout (float2 units):
//   [0,64)      radix-8 Ls=8 table  w[p][u] = exp(-2pi*i*p*u/64)   (col FFTs)
//   [64,320)    radix-16 stage-1    w[p][u] = exp(-2pi*i*p*u/256)  p,u<16
//   [320,4416)  radix-16 stage-2    w[p][u] = exp(-2pi*i*p*u/4096) p<256,u<16
// ek: expk[k] = (cos(pi*k/8192), sin(pi*k/8192)), 4096 entries.
__global__ __launch_bounds__(256) void setup_tables(float* __restrict__ tw,
                                                    float* __restrict__ ek) {
    int idx = blockIdx.x * 256 + threadIdx.x;
    if (idx < 4416) {
        int p, u; float denom;
        if (idx < 64)       { p = idx >> 3;         u = idx & 7;  denom = 64.0f; }
        else if (idx < 320) { int r = idx - 64;  p = r >> 4; u = r & 15; denom = 256.0f; }
        else                { int r = idx - 320; p = r >> 4; u = r & 15; denom = 4096.0f; }
        float phi = (float)(p * u) * (6.283185307179586f / denom);
        float s, c; __sincosf(phi, &s, &c);
        tw[2 * idx]     = c;
        tw[2 * idx + 1] = -s;
    } else if (idx < 8512) {
        int k = idx - 4416;
        float th = (float)k * (3.141592653589793f / 8192.0f);
        float s, c; __sincosf(th, &s, &c);
        ek[2 * k]     = c;
        ek[2 * k + 1] = s;
    }
}

#define RADIX8(Xv, E0, E1, E2, E3, O0, g1, g2, g3)                             \
    float2 t0 = cadd(Xv[0], Xv[4]), t1 = csub(Xv[0], Xv[4]);                   \
    float2 t2 = cadd(Xv[2], Xv[6]), t3 = csub(Xv[2], Xv[6]);                   \
    float2 E0 = cadd(t0, t2), E2 = csub(t0, t2);                               \
    float2 r3 = rotm(t3);                                                      \
    float2 E1 = cadd(t1, r3), E3 = csub(t1, r3);                               \
    float2 s0 = cadd(Xv[1], Xv[5]), s1 = csub(Xv[1], Xv[5]);                   \
    float2 s2 = cadd(Xv[3], Xv[7]), s3 = csub(Xv[3], Xv[7]);                   \
    float2 O0 = cadd(s0, s2), O2 = csub(s0, s2);                               \
    float2 r7 = rotm(s3);                                                      \
    float2 O1 = cadd(s1, r7), O3 = csub(s1, r7);                               \
    const float SQ = 0.7071067811865476f;                                      \
    float2 g1; g1.x = SQ * (O1.x + O1.y); g1.y = SQ * (O1.y - O1.x);           \
    float2 g2 = rotm(O2);                                                      \
    float2 g3; g3.x = SQ * (O3.y - O3.x); g3.y = -SQ * (O3.x + O3.y);

// In-place 16-pt DFT: X[i] = E[i&7] +/- W16^i * O[i&7], E/O = DFT8(even/odd).
__device__ __forceinline__ void dft16(float2* x) {
    float2 E[8], O[8];
    {
        float2 a[8];
        #pragma unroll
        for (int m = 0; m < 8; ++m) a[m] = x[2 * m];
        RADIX8(a, E0, E1, E2, E3, O0, g1, g2, g3)
        E[0] = cadd(E0, O0); E[1] = cadd(E1, g1);
        E[2] = cadd(E2, g2); E[3] = cadd(E3, g3);
        E[4] = csub(E0, O0); E[5] = csub(E1, g1);
        E[6] = csub(E2, g2); E[7] = csub(E3, g3);
    }
    {
        float2 a[8];
        #pragma unroll
        for (int m = 0; m < 8; ++m) a[m] = x[2 * m + 1];
        RADIX8(a, E0, E1, E2, E3, O0, g1, g2, g3)
        O[0] = cadd(E0, O0); O[1] = cadd(E1, g1);
        O[2] = cadd(E2, g2); O[3] = cadd(E3, g3);
        O[4] = csub(E0, O0); O[5] = csub(E1, g1);
        O[6] = csub(E2, g2); O[7] = csub(E3, g3);
    }
    const float2 W1 = { 0.9238795325112867f, -0.3826834323650898f};
    const float2 W2 = { 0.7071067811865476f, -0.7071067811865476f};
    const float2 W3 = { 0.3826834323650898f, -0.9238795325112867f};
    const float2 W5 = {-0.3826834323650898f, -0.9238795325112867f};
    const float2 W6 = {-0.7071067811865476f, -0.7071067811865476f};
    const float2 W7 = {-0.9238795325112867f, -0.3826834323650898f};
    float2 t;
    x[0] = cadd(E[0], O[0]);  x[8]  = csub(E[0], O[0]);
    t = cmulc(O[1], W1); x[1] = cadd(E[1], t); x[9]  = csub(E[1], t);
    t = cmulc(O[2], W2); x[2] = cadd(E[2], t); x[10] = csub(E[2], t);
    t = cmulc(O[3], W3); x[3] = cadd(E[3], t); x[11] = csub(E[3], t);
    t = rotm(O[4]);      x[4] = cadd(E[4], t); x[12] = csub(E[4], t);
    t = cmulc(O[5], W5); x[5] = cadd(E[5], t); x[13] = csub(E[5], t);
    t = cmulc(O[6], W6); x[6] = cadd(E[6], t); x[14] = csub(E[6], t);
    t = cmulc(O[7], W7); x[7] = cadd(E[7], t); x[15] = csub(E[7], t);
}

// One workgroup (256 thr) = TWO input rows (2b, 2b+1), pair-packed.
// Radix-16 Stockham: stages Ls = 1, 16, 256; thread j reads j+256k each
// stage; stage-2 read set == write set (own slots), outputs kept in regs.
// Stage 0 applies the row Makhoul gather; output rows written PERMUTED for
// the column-Makhoul: row 2b -> b, row 2b+1 -> 4095-b.
__global__ __launch_bounds__(256) void dct_rows(const float* __restrict__ In,
                                                float* __restrict__ Out,
                                                const float* __restrict__ tw,
                                                const float* __restrict__ ek) {
    __shared__ float2 buf[NF];   // 32 KB
    const int j = threadIdx.x;   // 0..255
    const int b = blockIdx.x;    // 0..2047
    const float* in0 = In + (size_t)(2 * b) * NF;
    const float* in1 = in0 + NF;
    float* out0 = Out + (size_t)b * NF;            // sigma^-1(2b)   = b
    float* out1 = Out + (size_t)(4095 - b) * NF;   // sigma^-1(2b+1) = 4095-b

    float2 x[16];

    // ---- stage 0 (Ls=1): Makhoul gather, DFT16, write 16j+i
    #pragma unroll
    for (int k = 0; k < 16; ++k) {
        int n = j + 256 * k;
        int idx = (n < 2048) ? (2 * n) : (8191 - 2 * n);
        x[k].x = in0[idx];
        x[k].y = in1[idx];
    }
    dft16(x);
    #pragma unroll
    for (int i = 0; i < 16; ++i)
        buf[physi(16 * j + i)] = x[i];
    __syncthreads();

    // ---- stage 1 (Ls=16): read j+256k, twiddle, DFT16, write p+256q+16i
    {
        const int p = j & 15, q = j >> 4;
        #pragma unroll
        for (int k = 0; k < 16; ++k)
            x[k] = buf[physi(j + 256 * k)];
        const float2* twp = (const float2*)tw + 64 + p * 16;
        #pragma unroll
        for (int k = 1; k < 16; ++k)
            x[k] = cmulc(x[k], twp[k]);
        dft16(x);
        __syncthreads();
        int wb = p + 256 * q;
        #pragma unroll
        for (int i = 0; i < 16; ++i)
            buf[physi(wb + 16 * i)] = x[i];
        __syncthreads();
    }

    // ---- stage 2 (Ls=256, p=j): read/write own slots j+256i, no mid barrier
    {
        #pragma unroll
        for (int k = 0; k < 16; ++k)
            x[k] = buf[physi(j + 256 * k)];
        const float2* twp = (const float2*)tw + 320 + j * 16;
        #pragma unroll
        for (int k = 1; k < 16; ++k)
            x[k] = cmulc(x[k], twp[k]);
        dft16(x);
        #pragma unroll
        for (int i = 0; i < 16; ++i)
            buf[physi(j + 256 * i)] = x[i];   // own slots only
    }
    __syncthreads();

    // ---- epilogue: Zk from regs; partner Zm via LDS
    #pragma unroll
    for (int i = 0; i < 16; ++i) {
        int k = j + 256 * i;
        int m = (NF - k) & (NF - 1);
        float2 Zk = x[i];
        float2 Zm = buf[physi(m)];
        float2 E = ((const float2*)ek)[k];
        out0[k] = 0.5f * ((Zk.x + Zm.x) * E.x + (Zk.y - Zm.y) * E.y);
        out1[k] = 0.5f * ((Zk.y + Zm.y) * E.x - (Zk.x - Zm.x) * E.y);
    }
}

// ---------------------------------------------------------------------------
// Column pass, four-step step 1. One block = one n1 residue (blockIdx.y) x
// one 64-column tile (blockIdx.x). 256 threads: cp = t&31 (column float2,
// lane-fast => conflict-free LDS, 256 B global segments), j = t>>5.
// Four-step twiddle W4096^{n1*k2} comes from a 64-entry LDS table computed
// once per block (64 sincos instead of 2048).
// ---------------------------------------------------------------------------
__global__ __launch_bounds__(256) void col_fft1(const float* __restrict__ V,
                                                float* __restrict__ S,
                                                const float* __restrict__ tw) {
    __shared__ float2 T[64][32];   // 16 KB
    __shared__ float2 w64[64];
    const int ct = blockIdx.x, n1 = blockIdx.y;
    const int t = threadIdx.x;
    const int cp = t & 31, j = t >> 5;
    const float2* inb = (const float2*)V + (size_t)ct * 32 + cp;

    if (t < 64) {
        int m = (n1 * t) & 4095;
        float phi = (float)m * -1.5339807878856412e-3f;  // -2pi/4096
        float s, c; __sincosf(phi, &s, &c);
        float2 w; w.x = c; w.y = s;
        w64[t] = w;
    }

    float2 x[8];
    #pragma unroll
    for (int k = 0; k < 8; ++k) {
        int row = n1 + 64 * (j + 8 * k);
        x[k] = inb[(size_t)row * 2048];
    }
    {   // stage A (Ls=1): outputs to LDS rows 8j+i
        RADIX8(x, E0, E1, E2, E3, O0, g1, g2, g3)
        T[8 * j + 0][cp] = cadd(E0, O0);
        T[8 * j + 1][cp] = cadd(E1, g1);
        T[8 * j + 2][cp] = cadd(E2, g2);
        T[8 * j + 3][cp] = cadd(E3, g3);
        T[8 * j + 4][cp] = csub(E0, O0);
        T[8 * j + 5][cp] = csub(E1, g1);
        T[8 * j + 6][cp] = csub(E2, g2);
        T[8 * j + 7][cp] = csub(E3, g3);
    }
    __syncthreads();

    float2 o[8];
    {   // stage B (Ls=8): p=j, natural-order outputs k2 = j+8i
        #pragma unroll
        for (int k = 0; k < 8; ++k)
            x[k] = T[j + 8 * k][cp];
        const float2* twp = (const float2*)tw + j * 8;   // Ls=8 section
        #pragma unroll
        for (int k = 1; k < 8; ++k)
            x[k] = cmulc(x[k], twp[k]);
        RADIX8(x, E0, E1, E2, E3, O0, g1, g2, g3)
        o[0] = cadd(E0, O0); o[1] = cadd(E1, g1);
        o[2] = cadd(E2, g2); o[3] = cadd(E3, g3);
        o[4] = csub(E0, O0); o[5] = csub(E1, g1);
        o[6] = csub(E2, g2); o[7] = csub(E3, g3);
    }

    // four-step twiddle from LDS, store to S row 64*k2+n1
    float2* outb = (float2*)S + (size_t)ct * 32 + cp;
    #pragma unroll
    for (int i = 0; i < 8; ++i) {
        int k2 = j + 8 * i;
        float2 h = cmulc(o[i], w64[k2]);
        outb[(size_t)(64 * k2 + n1) * 2048] = h;
    }
}

// ---------------------------------------------------------------------------
// Column pass, four-step step 2 + Hermitian/expk epilogue. One block = the
// k2-pair {ga, gb} = {bp, 64-bp} (bp=0 -> {0,32}) x one 64-column tile.
// 512 threads: gi = t>>8 selects the group, j = (t>>5)&7, cp = t&31.
// ---------------------------------------------------------------------------
__global__ __launch_bounds__(512) void col_fft2(const float* __restrict__ S,
                                                float* __restrict__ Out,
                                                const float* __restrict__ tw,
                                                const float* __restrict__ ek) {
    __shared__ float2 T[2][64][32];   // 32 KB
    const int ct = blockIdx.x, bp = blockIdx.y;
    const int ga = bp, gb = (bp == 0) ? 32 : 64 - bp;
    const int t = threadIdx.x;
    const int cp = t & 31, j = (t >> 5) & 7, gi = t >> 8;
    const int g = gi ? gb : ga;
    const float2* inb = (const float2*)S + (size_t)ct * 32 + cp;

    float2 x[8];
    #pragma unroll
    for (int k = 0; k < 8; ++k)
        x[k] = inb[(size_t)(64 * g + j + 8 * k) * 2048];
    {   // stage A
        RADIX8(x, E0, E1, E2, E3, O0, g1, g2, g3)
        T[gi][8 * j + 0][cp] = cadd(E0, O0);
        T[gi][8 * j + 1][cp] = cadd(E1, g1);
        T[gi][8 * j + 2][cp] = cadd(E2, g2);
        T[gi][8 * j + 3][cp] = cadd(E3, g3);
        T[gi][8 * j + 4][cp] = csub(E0, O0);
        T[gi][8 * j + 5][cp] = csub(E1, g1);
        T[gi][8 * j + 6][cp] = csub(E2, g2);
        T[gi][8 * j + 7][cp] = csub(E3, g3);
    }
    __syncthreads();

    float2 o[8];
    {   // stage B: read rows j+8k, write rows j+8i (same per-thread set)
        #pragma unroll
        for (int k = 0; k < 8; ++k)
            x[k] = T[gi][j + 8 * k][cp];
        const float2* twp = (const float2*)tw + j * 8;
        #pragma unroll
        for (int k = 1; k < 8; ++k)
            x[k] = cmulc(x[k], twp[k]);
        RADIX8(x, E0, E1, E2, E3, O0, g1, g2, g3)
        o[0] = cadd(E0, O0); o[1] = cadd(E1, g1);
        o[2] = cadd(E2, g2); o[3] = cadd(E3, g3);
        o[4] = csub(E0, O0); o[5] = csub(E1, g1);
        o[6] = csub(E2, g2); o[7] = csub(E3, g3);
        #pragma unroll
        for (int i = 0; i < 8; ++i)
            T[gi][j + 8 * i][cp] = o[i];
    }
    __syncthreads();

    // epilogue: k = 64*(j+8i)+g; partner m = (4096-k)&4095 is in this block
    float2* outb = (float2*)Out + (size_t)ct * 32 + cp;
    #pragma unroll
    for (int i = 0; i < 8; ++i) {
        int k = 64 * (j + 8 * i) + g;
        int m = (NF - k) & (NF - 1);
        int gp = m & 63, k1p = m >> 6;
        float2 Zk = o[i];
        float2 Zm = T[(gp == ga) ? 0 : 1][k1p][cp];
        float2 E = ((const float2*)ek)[k];
        float2 r;
        r.x = 0.5f * ((Zk.x + Zm.x) * E.x + (Zk.y - Zm.y) * E.y);
        r.y = 0.5f * ((Zk.y + Zm.y) * E.x - (Zk.x - Zm.x) * E.y);
        outb[(size_t)k * 2048] = r;   // cols 2*(ct*32+cp), +1
    }
}

extern "C" void kernel_launch(void* const* d_in, const int* in_sizes, int n_in,
                              void* d_out, int out_size, void* d_ws, size_t ws_size,
                              hipStream_t stream) {
    const float* x = (const float*)d_in[0];
    float* out = (float*)d_out;

    float* tw = (float*)d_ws;           // 4416 float2 = 8832 floats
    float* ek = tw + 8832;              // 4096 float2 = 8192 floats
    float* B1 = ek + 8192;              // 4096*4096 floats (64 MB)
    if (ws_size < (size_t)68096 + (size_t)NF * NF * sizeof(float)) return;

    setup_tables<<<34, 256, 0, stream>>>(tw, ek);
    dct_rows<<<NF / 2, 256, 0, stream>>>(x, out, tw, ek);        // out = V
    col_fft1<<<dim3(64, 64), 256, 0, stream>>>(out, B1, tw);     // B1  = H
    col_fft2<<<dim3(64, 32), 512, 0, stream>>>(B1, out, tw, ek); // out = Z
}

// Round 6
// 167.567 us; speedup vs baseline: 1.1854x; 1.0086x over previous
//
#include <hip/hip_runtime.h>
#include <stdint.h>

// ---------------------------------------------------------------------------
// 2D DCT-II (unnormalized, 4096x4096 fp32), FFT path, v7b (v7 + gather fix:
// chunk index is j + 256*c (1024 float4 chunks/row), was j + 64*c -> half of
// LDS uninitialized -> absmax 2.5e6):
//   (a) dct_rows stage-0: Makhoul gather as dense float4 global loads + LDS
//       scatter (was 32 stride-2 scalar loads/thread).
//   (b) col_fft1 widened to TWO column-pairs per thread: float4 (16 B/lane)
//       global loads/stores, halved VMEM inst count, 2 independent FFTs.
//   col_fft2 unchanged.
// Data flow (d_out used as scratch):
//   1. dct_rows   : x  -> out  (V = row-DCT, column-Makhoul folded into the
//                   output row index: row 2b -> b, row 2b+1 -> 4095-b)
//   2. col_fft1   : out -> B1  (per n1: 64-pt FFT over n2 + 4-step twiddle;
//                   H[n1][k2] at row 64*k2+n1 so pass 3 reads contiguous)
//   3. col_fft2   : B1 -> out  (per k2-pair {k2,64-k2}: 64-pt FFT over n1,
//                   Hermitian pairs block-local, expk epilogue, real out)
// ---------------------------------------------------------------------------

#define NF 4096

__device__ __forceinline__ int physi(int e) { return e ^ ((e >> 4) & 15); }

__device__ __forceinline__ float2 cadd(float2 a, float2 b) {
    float2 r; r.x = a.x + b.x; r.y = a.y + b.y; return r;
}
__device__ __forceinline__ float2 csub(float2 a, float2 b) {
    float2 r; r.x = a.x - b.x; r.y = a.y - b.y; return r;
}
__device__ __forceinline__ float2 cmulc(float2 a, float2 b) {
    float2 r; r.x = a.x * b.x - a.y * b.y; r.y = a.x * b.y + a.y * b.x; return r;
}
__device__ __forceinline__ float2 rotm(float2 a) {  // -i * a
    float2 r; r.x = a.y; r.y = -a.x; return r;
}

// tw layout (float2 units):
//   [0,64)      radix-8 Ls=8 table  w[p][u] = exp(-2pi*i*p*u/64)   (col FFTs)
//   [64,320)    radix-16 stage-1    w[p][u] = exp(-2pi*i*p*u/256)  p,u<16
//   [320,4416)  radix-16 stage-2    w[p][u] = exp(-2pi*i*p*u/4096) p<256,u<16
// ek: expk[k] = (cos(pi*k/8192), sin(pi*k/8192)), 4096 entries.
__global__ __launch_bounds__(256) void setup_tables(float* __restrict__ tw,
                                                    float* __restrict__ ek) {
    int idx = blockIdx.x * 256 + threadIdx.x;
    if (idx < 4416) {
        int p, u; float denom;
        if (idx < 64)       { p = idx >> 3;         u = idx & 7;  denom = 64.0f; }
        else if (idx < 320) { int r = idx - 64;  p = r >> 4; u = r & 15; denom = 256.0f; }
        else                { int r = idx - 320; p = r >> 4; u = r & 15; denom = 4096.0f; }
        float phi = (float)(p * u) * (6.283185307179586f / denom);
        float s, c; __sincosf(phi, &s, &c);
        tw[2 * idx]     = c;
        tw[2 * idx + 1] = -s;
    } else if (idx < 8512) {
        int k = idx - 4416;
        float th = (float)k * (3.141592653589793f / 8192.0f);
        float s, c; __sincosf(th, &s, &c);
        ek[2 * k]     = c;
        ek[2 * k + 1] = s;
    }
}

#define RADIX8(Xv, E0, E1, E2, E3, O0, g1, g2, g3)                             \
    float2 t0 = cadd(Xv[0], Xv[4]), t1 = csub(Xv[0], Xv[4]);                   \
    float2 t2 = cadd(Xv[2], Xv[6]), t3 = csub(Xv[2], Xv[6]);                   \
    float2 E0 = cadd(t0, t2), E2 = csub(t0, t2);                               \
    float2 r3 = rotm(t3);                                                      \
    float2 E1 = cadd(t1, r3), E3 = csub(t1, r3);                               \
    float2 s0 = cadd(Xv[1], Xv[5]), s1 = csub(Xv[1], Xv[5]);                   \
    float2 s2 = cadd(Xv[3], Xv[7]), s3 = csub(Xv[3], Xv[7]);                   \
    float2 O0 = cadd(s0, s2), O2 = csub(s0, s2);                               \
    float2 r7 = rotm(s3);                                                      \
    float2 O1 = cadd(s1, r7), O3 = csub(s1, r7);                               \
    const float SQ = 0.7071067811865476f;                                      \
    float2 g1; g1.x = SQ * (O1.x + O1.y); g1.y = SQ * (O1.y - O1.x);           \
    float2 g2 = rotm(O2);                                                      \
    float2 g3; g3.x = SQ * (O3.y - O3.x); g3.y = -SQ * (O3.x + O3.y);

// Full radix-8 butterfly to out[8] (reusable twice in one scope).
#define RADIX8_OUT(Xv, Ov)                                                     \
    {                                                                          \
        RADIX8(Xv, E0, E1, E2, E3, O0, g1, g2, g3)                             \
        Ov[0] = cadd(E0, O0); Ov[1] = cadd(E1, g1);                            \
        Ov[2] = cadd(E2, g2); Ov[3] = cadd(E3, g3);                            \
        Ov[4] = csub(E0, O0); Ov[5] = csub(E1, g1);                            \
        Ov[6] = csub(E2, g2); Ov[7] = csub(E3, g3);                            \
    }

// In-place 16-pt DFT: X[i] = E[i&7] +/- W16^i * O[i&7], E/O = DFT8(even/odd).
__device__ __forceinline__ void dft16(float2* x) {
    float2 E[8], O[8];
    {
        float2 a[8];
        #pragma unroll
        for (int m = 0; m < 8; ++m) a[m] = x[2 * m];
        RADIX8_OUT(a, E)
    }
    {
        float2 a[8];
        #pragma unroll
        for (int m = 0; m < 8; ++m) a[m] = x[2 * m + 1];
        RADIX8_OUT(a, O)
    }
    const float2 W1 = { 0.9238795325112867f, -0.3826834323650898f};
    const float2 W2 = { 0.7071067811865476f, -0.7071067811865476f};
    const float2 W3 = { 0.3826834323650898f, -0.9238795325112867f};
    const float2 W5 = {-0.3826834323650898f, -0.9238795325112867f};
    const float2 W6 = {-0.7071067811865476f, -0.7071067811865476f};
    const float2 W7 = {-0.9238795325112867f, -0.3826834323650898f};
    float2 t;
    x[0] = cadd(E[0], O[0]);  x[8]  = csub(E[0], O[0]);
    t = cmulc(O[1], W1); x[1] = cadd(E[1], t); x[9]  = csub(E[1], t);
    t = cmulc(O[2], W2); x[2] = cadd(E[2], t); x[10] = csub(E[2], t);
    t = cmulc(O[3], W3); x[3] = cadd(E[3], t); x[11] = csub(E[3], t);
    t = rotm(O[4]);      x[4] = cadd(E[4], t); x[12] = csub(E[4], t);
    t = cmulc(O[5], W5); x[5] = cadd(E[5], t); x[13] = csub(E[5], t);
    t = cmulc(O[6], W6); x[6] = cadd(E[6], t); x[14] = csub(E[6], t);
    t = cmulc(O[7], W7); x[7] = cadd(E[7], t); x[15] = csub(E[7], t);
}

// One workgroup (256 thr) = TWO input rows (2b, 2b+1), pair-packed.
// v7 stage-0: dense float4 loads; thread j loads float4 chunks ch = j+256c
// (c=0..3; 1024 chunks tile the row exactly) of both rows and scatters pair
// z[n] into LDS at the Makhoul slot:
//   floats p = 4*ch+m:  p even -> n = p/2;  p odd -> n = (8191-p)/2
//   => n ∈ {2ch, 2ch+1, 4095-2ch, 4094-2ch}, each n written exactly once.
// Then radix-16 Stockham entirely from LDS: stages Ls = 1, 16, 256.
// Output rows written PERMUTED for the column-Makhoul: 2b -> b, 2b+1 -> 4095-b.
__global__ __launch_bounds__(256) void dct_rows(const float* __restrict__ In,
                                                float* __restrict__ Out,
                                                const float* __restrict__ tw,
                                                const float* __restrict__ ek) {
    __shared__ float2 buf[NF];   // 32 KB
    const int j = threadIdx.x;   // 0..255
    const int b = blockIdx.x;    // 0..2047
    const float* in0 = In + (size_t)(2 * b) * NF;
    const float* in1 = in0 + NF;
    float* out0 = Out + (size_t)b * NF;            // sigma^-1(2b)   = b
    float* out1 = Out + (size_t)(4095 - b) * NF;   // sigma^-1(2b+1) = 4095-b

    // ---- gather: dense float4 loads, Makhoul scatter into LDS
    const float4* i40 = (const float4*)in0;
    const float4* i41 = (const float4*)in1;
    #pragma unroll
    for (int c = 0; c < 4; ++c) {
        float4 a0 = i40[j + 256 * c];
        float4 a1 = i41[j + 256 * c];
        int nb = 2 * j + 512 * c;              // = 2*ch
        float2 z0; z0.x = a0.x; z0.y = a1.x;   // p=4ch     even -> n=nb
        float2 z1; z1.x = a0.z; z1.y = a1.z;   // p+2       even -> n=nb+1
        float2 z2; z2.x = a0.y; z2.y = a1.y;   // p+1       odd  -> 4095-nb
        float2 z3; z3.x = a0.w; z3.y = a1.w;   // p+3       odd  -> 4094-nb
        buf[physi(nb)]        = z0;
        buf[physi(nb + 1)]    = z1;
        buf[physi(4095 - nb)] = z2;
        buf[physi(4094 - nb)] = z3;
    }
    __syncthreads();

    float2 x[16];

    // ---- stage 0 (Ls=1): read j+256k from LDS, DFT16, write 16j+i
    #pragma unroll
    for (int k = 0; k < 16; ++k)
        x[k] = buf[physi(j + 256 * k)];
    dft16(x);
    __syncthreads();
    #pragma unroll
    for (int i = 0; i < 16; ++i)
        buf[physi(16 * j + i)] = x[i];
    __syncthreads();

    // ---- stage 1 (Ls=16): read j+256k, twiddle, DFT16, write p+256q+16i
    {
        const int p = j & 15, q = j >> 4;
        #pragma unroll
        for (int k = 0; k < 16; ++k)
            x[k] = buf[physi(j + 256 * k)];
        const float2* twp = (const float2*)tw + 64 + p * 16;
        #pragma unroll
        for (int k = 1; k < 16; ++k)
            x[k] = cmulc(x[k], twp[k]);
        dft16(x);
        __syncthreads();
        int wb = p + 256 * q;
        #pragma unroll
        for (int i = 0; i < 16; ++i)
            buf[physi(wb + 16 * i)] = x[i];
        __syncthreads();
    }

    // ---- stage 2 (Ls=256, p=j): read/write own slots j+256i, no mid barrier
    {
        #pragma unroll
        for (int k = 0; k < 16; ++k)
            x[k] = buf[physi(j + 256 * k)];
        const float2* twp = (const float2*)tw + 320 + j * 16;
        #pragma unroll
        for (int k = 1; k < 16; ++k)
            x[k] = cmulc(x[k], twp[k]);
        dft16(x);
        #pragma unroll
        for (int i = 0; i < 16; ++i)
            buf[physi(j + 256 * i)] = x[i];   // own slots only
    }
    __syncthreads();

    // ---- epilogue: Zk from regs; partner Zm via LDS
    #pragma unroll
    for (int i = 0; i < 16; ++i) {
        int k = j + 256 * i;
        int m = (NF - k) & (NF - 1);
        float2 Zk = x[i];
        float2 Zm = buf[physi(m)];
        float2 E = ((const float2*)ek)[k];
        out0[k] = 0.5f * ((Zk.x + Zm.x) * E.x + (Zk.y - Zm.y) * E.y);
        out1[k] = 0.5f * ((Zk.y + Zm.y) * E.x - (Zk.x - Zm.x) * E.y);
    }
}

// ---------------------------------------------------------------------------
// Column pass, four-step step 1, v7: TWO column-pairs per thread (float4 =
// 16 B/lane). One block = one n1 residue (blockIdx.y) x one 128-float-column
// tile (blockIdx.x, 0..31). 256 threads: cp4 = t&31 (float4 column within
// tile), j = t>>5 (butterfly job). Reads V rows n1+64*n2, 64-pt FFT over n2
// (two independent FFTs per thread), four-step twiddle from a 64-entry LDS
// table, stores H to S row 64*k2+n1.
// ---------------------------------------------------------------------------
__global__ __launch_bounds__(256) void col_fft1(const float* __restrict__ V,
                                                float* __restrict__ S,
                                                const float* __restrict__ tw) {
    __shared__ float2 T[64][64];   // 32 KB: [row][col-pair], pairs 2*cp4+{0,1}
    __shared__ float2 w64[64];
    const int ct = blockIdx.x, n1 = blockIdx.y;
    const int t = threadIdx.x;
    const int cp4 = t & 31, j = t >> 5;
    const float4* in4 = (const float4*)V + (size_t)ct * 32 + cp4;

    if (t < 64) {
        int m = (n1 * t) & 4095;
        float phi = (float)m * -1.5339807878856412e-3f;  // -2pi/4096
        float s, c; __sincosf(phi, &s, &c);
        float2 w; w.x = c; w.y = s;
        w64[t] = w;
    }

    float2 xA[8], xB[8];
    #pragma unroll
    for (int k = 0; k < 8; ++k) {
        float4 v4 = in4[(size_t)(n1 + 64 * (j + 8 * k)) * 1024];
        xA[k].x = v4.x; xA[k].y = v4.y;
        xB[k].x = v4.z; xB[k].y = v4.w;
    }
    {   // stage A (Ls=1): outputs to LDS rows 8j+i, both pairs as one float4
        float2 rA[8], rB[8];
        RADIX8_OUT(xA, rA)
        RADIX8_OUT(xB, rB)
        #pragma unroll
        for (int i = 0; i < 8; ++i) {
            float4 w; w.x = rA[i].x; w.y = rA[i].y; w.z = rB[i].x; w.w = rB[i].y;
            *(float4*)&T[8 * j + i][2 * cp4] = w;
        }
    }
    __syncthreads();

    float2 oA[8], oB[8];
    {   // stage B (Ls=8): p=j, natural-order outputs k2 = j+8i
        #pragma unroll
        for (int k = 0; k < 8; ++k) {
            float4 v4 = *(const float4*)&T[j + 8 * k][2 * cp4];
            xA[k].x = v4.x; xA[k].y = v4.y;
            xB[k].x = v4.z; xB[k].y = v4.w;
        }
        const float2* twp = (const float2*)tw + j * 8;   // Ls=8 section
        #pragma unroll
        for (int k = 1; k < 8; ++k) {
            xA[k] = cmulc(xA[k], twp[k]);
            xB[k] = cmulc(xB[k], twp[k]);
        }
        RADIX8_OUT(xA, oA)
        RADIX8_OUT(xB, oB)
    }

    // four-step twiddle from LDS, store both pairs to S row 64*k2+n1
    float4* out4 = (float4*)S + (size_t)ct * 32 + cp4;
    #pragma unroll
    for (int i = 0; i < 8; ++i) {
        int k2 = j + 8 * i;
        float2 hA = cmulc(oA[i], w64[k2]);
        float2 hB = cmulc(oB[i], w64[k2]);
        float4 w; w.x = hA.x; w.y = hA.y; w.z = hB.x; w.w = hB.y;
        out4[(size_t)(64 * k2 + n1) * 1024] = w;
    }
}

// ---------------------------------------------------------------------------
// Column pass, four-step step 2 + Hermitian/expk epilogue. One block = the
// k2-pair {ga, gb} = {bp, 64-bp} (bp=0 -> {0,32}) x one 64-column tile.
// 512 threads: gi = t>>8 selects the group, j = (t>>5)&7, cp = t&31.
// ---------------------------------------------------------------------------
__global__ __launch_bounds__(512) void col_fft2(const float* __restrict__ S,
                                                float* __restrict__ Out,
                                                const float* __restrict__ tw,
                                                const float* __restrict__ ek) {
    __shared__ float2 T[2][64][32];   // 32 KB
    const int ct = blockIdx.x, bp = blockIdx.y;
    const int ga = bp, gb = (bp == 0) ? 32 : 64 - bp;
    const int t = threadIdx.x;
    const int cp = t & 31, j = (t >> 5) & 7, gi = t >> 8;
    const int g = gi ? gb : ga;
    const float2* inb = (const float2*)S + (size_t)ct * 32 + cp;

    float2 x[8];
    #pragma unroll
    for (int k = 0; k < 8; ++k)
        x[k] = inb[(size_t)(64 * g + j + 8 * k) * 2048];
    {   // stage A
        float2 r[8];
        RADIX8_OUT(x, r)
        #pragma unroll
        for (int i = 0; i < 8; ++i)
            T[gi][8 * j + i][cp] = r[i];
    }
    __syncthreads();

    float2 o[8];
    {   // stage B: read rows j+8k, write rows j+8i (same per-thread set)
        #pragma unroll
        for (int k = 0; k < 8; ++k)
            x[k] = T[gi][j + 8 * k][cp];
        const float2* twp = (const float2*)tw + j * 8;
        #pragma unroll
        for (int k = 1; k < 8; ++k)
            x[k] = cmulc(x[k], twp[k]);
        RADIX8_OUT(x, o)
        #pragma unroll
        for (int i = 0; i < 8; ++i)
            T[gi][j + 8 * i][cp] = o[i];
    }
    __syncthreads();

    // epilogue: k = 64*(j+8i)+g; partner m = (4096-k)&4095 is in this block
    float2* outb = (float2*)Out + (size_t)ct * 32 + cp;
    #pragma unroll
    for (int i = 0; i < 8; ++i) {
        int k = 64 * (j + 8 * i) + g;
        int m = (NF - k) & (NF - 1);
        int gp = m & 63, k1p = m >> 6;
        float2 Zk = o[i];
        float2 Zm = T[(gp == ga) ? 0 : 1][k1p][cp];
        float2 E = ((const float2*)ek)[k];
        float2 r;
        r.x = 0.5f * ((Zk.x + Zm.x) * E.x + (Zk.y - Zm.y) * E.y);
        r.y = 0.5f * ((Zk.y + Zm.y) * E.x - (Zk.x - Zm.x) * E.y);
        outb[(size_t)k * 2048] = r;   // cols 2*(ct*32+cp), +1
    }
}

extern "C" void kernel_launch(void* const* d_in, const int* in_sizes, int n_in,
                              void* d_out, int out_size, void* d_ws, size_t ws_size,
                              hipStream_t stream) {
    const float* x = (const float*)d_in[0];
    float* out = (float*)d_out;

    float* tw = (float*)d_ws;           // 4416 float2 = 8832 floats
    float* ek = tw + 8832;              // 4096 float2 = 8192 floats
    float* B1 = ek + 8192;              // 4096*4096 floats (64 MB)
    if (ws_size < (size_t)68096 + (size_t)NF * NF * sizeof(float)) return;

    setup_tables<<<34, 256, 0, stream>>>(tw, ek);
    dct_rows<<<NF / 2, 256, 0, stream>>>(x, out, tw, ek);        // out = V
    col_fft1<<<dim3(32, 64), 256, 0, stream>>>(out, B1, tw);     // B1  = H
    col_fft2<<<dim3(64, 32), 512, 0, stream>>>(B1, out, tw, ek); // out = Z
}